// Round 6
// baseline (1652.831 us; speedup 1.0000x reference)
//
#include <hip/hip_runtime.h>

#define SEQ   512
#define BATCH 256
#define DIN   128
#define HID   256
#define NB    4      // batch chains interleaved per wave (ILP to fill stalls)

__device__ __forceinline__ float dot4(float4 a, float4 b) {
    return fmaf(a.x, b.x, fmaf(a.y, b.y, fmaf(a.z, b.z, a.w * b.w)));
}
__device__ __forceinline__ float tanh_(float x) {      // round-2 bitwise
    float ax = fabsf(x);
    float e  = __expf(2.0f * ax);
    float r  = 1.0f - 2.0f / (e + 1.0f);
    return copysignf(r, x);
}
template <int CTRL>
__device__ __forceinline__ float dppf(float v) {
    return __int_as_float(__builtin_amdgcn_mov_dpp(__float_as_int(v), CTRL, 0xF, 0xF, false));
}
template <int CTRL>
__device__ __forceinline__ float4 dpp4(float4 v) {
    return make_float4(dppf<CTRL>(v.x), dppf<CTRL>(v.y), dppf<CTRL>(v.z), dppf<CTRL>(v.w));
}
__device__ __forceinline__ float swap16_sum(float v) {
    float a = v, b;
    asm("v_mov_b32 %1, %0\n\tv_permlane16_swap_b32 %0, %1" : "+v"(a), "=&v"(b));
    return a + b;
}
__device__ __forceinline__ float swap32_sum(float v) {
    float a = v, b;
    asm("v_mov_b32 %1, %0\n\tv_permlane32_swap_b32 %0, %1" : "+v"(a), "=&v"(b));
    return a + b;
}
__device__ __forceinline__ float rdlanef(float v, int lane) {
    return __int_as_float(__builtin_amdgcn_readlane(__float_as_int(v), lane));
}

// ---------------------------------------------------------------------------
// Kernel 1: pre[s,b,p] = b_lin[p] + theta[p] + sum_d w_lin[p,d] * x[s,b,d]
// (bitwise-identical to round 2)
// ---------------------------------------------------------------------------
__global__ __launch_bounds__(256, 4) void pre_gemm(
    const float* __restrict__ x,      // (S,B,D)
    const float* __restrict__ w_lin,  // (16,384) x-part = [0:128)
    const float* __restrict__ b_lin,  // (16,)
    const float* __restrict__ theta,  // (16,)
    float* pre, int pstride)
{
    __shared__ float wlds[16 * 132];
    const int t = threadIdx.x;
    for (int i = t; i < 16 * 128; i += 256) {
        int pp = i >> 7, dd = i & 127;
        wlds[pp * 132 + dd] = w_lin[pp * 384 + dd];
    }
    __syncthreads();
    const int s = blockIdx.x >> 4;
    const int b = ((blockIdx.x & 15) << 4) + (t >> 4);
    const int p = t & 15;
    const float* xr = x + ((size_t)s * BATCH + b) * DIN;
    const float* wr = &wlds[p * 132];
    float acc = b_lin[p] + theta[p];
    #pragma unroll 8
    for (int d = 0; d < 32; ++d)
        acc += dot4(*(const float4*)(xr + d * 4), *(const float4*)(wr + d * 4));
    pre[((size_t)s * BATCH + b) * pstride + p] = acc;
}

// ---------------------------------------------------------------------------
// Kernel 2: recurrence — NB=4 batch chains per wave, no LDS, no barriers.
// Each chain's arithmetic is instruction-for-instruction the round-5/round-2
// bitwise sequence (passing numerics); the 4 independent chains live in one
// branchless basic block so the scheduler interleaves them to fill dependent-
// VALU stalls, DPP hazard slots, and weight-reload vmcnt waits.
// ---------------------------------------------------------------------------
__global__ __launch_bounds__(64, 1) void qlstm_rec(
    const float* __restrict__ w_lin,  // (16, 384), hx part = [128:384)
    const float* __restrict__ w_map,  // (4, 256, 4)
    const float* __restrict__ b_map,  // (4, 256)
    const float* pre, int pstride,    // may alias out (no restrict!)
    float* out)
{
    const int b0 = blockIdx.x * NB;
    const int l = threadIdx.x;        // 0..63
    const int a = l & 3;              // owned gate
    const int Q = l >> 2;             // quad; partial covers hx[16Q..16Q+15]
    const bool sg1 = (Q >> 1) & 1;
    const bool sg2 = (Q >> 2) & 1;
    const bool isT = (a == 2);

    // phase-1 weights: wh4[q][c] = Wh[p=4a+q][h = 16Q+4c .. +3]  (shared by all chains)
    float4 wh4[4][4];
    #pragma unroll
    for (int q = 0; q < 4; ++q)
        #pragma unroll
        for (int c = 0; c < 4; ++c)
            wh4[q][c] = *(const float4*)(w_lin + (4*a + q) * 384 + 128 + 16*Q + 4*c);

    // phase-2 weights/biases for own 4 h values (h = 4l+m)  (shared by all chains)
    float4 wm[4][4];
    float  bmv[4][4];
    #pragma unroll
    for (int g2 = 0; g2 < 4; ++g2) {
        #pragma unroll
        for (int m = 0; m < 4; ++m)
            wm[g2][m] = *(const float4*)(w_map + ((size_t)(g2 * 256 + 4*l + m)) * 4);
        float4 bq = *(const float4*)(b_map + g2 * 256 + 4*l);
        bmv[g2][0] = bq.x; bmv[g2][1] = bq.y; bmv[g2][2] = bq.z; bmv[g2][3] = bq.w;
    }

    const float nm = isT ? 2.0f : 1.0f;
    const size_t sstride = (size_t)BATCH * pstride;

    const float* pb[NB];
    float*       outp[NB];
    float4       px0[NB], px1[NB], hxv[NB];
    float        cxa[NB][4];
    #pragma unroll
    for (int k = 0; k < NB; ++k) {
        pb[k]   = pre + (size_t)(b0 + k) * pstride + 4*a;
        px0[k]  = *(const float4*)(pb[k]);
        px1[k]  = *(const float4*)(pb[k] + sstride);
        hxv[k]  = make_float4(0.f, 0.f, 0.f, 0.f);
        cxa[k][0] = cxa[k][1] = cxa[k][2] = cxa[k][3] = 0.f;
        outp[k] = out + (size_t)(b0 + k) * HID + 4*l;
    }

    float* out_hx = out + (size_t)SEQ * BATCH * HID;
    float* out_cx = out_hx + BATCH * HID;

    for (int s = 0; s < SEQ; ++s) {
        const int s2 = (s + 2 < SEQ) ? (s + 2) : (SEQ - 1);

        #pragma unroll
        for (int k = 0; k < NB; ++k) {
            const float4 pcur = px0[k];
            px0[k] = px1[k];
            px1[k] = *(const float4*)(pb[k] + (size_t)s2 * sstride);

            // ---- phase 1: quad-allgather hx ------------------------------
            const float4 h0 = dpp4<0x00>(hxv[k]);
            const float4 h1 = dpp4<0x55>(hxv[k]);
            const float4 h2 = dpp4<0xAA>(hxv[k]);
            const float4 h3 = dpp4<0xFF>(hxv[k]);

            // sig-permuted partial order + ror4/ror8/swap16/swap32 tree
            float pq[4];
            #pragma unroll
            for (int q = 0; q < 4; ++q) {
                const float d0 = dot4(wh4[q][0], h0);
                const float d1 = dot4(wh4[q][1], h1);
                const float d2 = dot4(wh4[q][2], h2);
                const float d3 = dot4(wh4[q][3], h3);
                const float A01 = d0 + d1;
                const float A23 = d2 + d3;
                const float t1 = sg2 ? A23 : A01;
                const float u  = sg2 ? (sg1 ? d1 : d0) : (sg1 ? d3 : d2);
                const float w  = sg2 ? (sg1 ? d0 : d1) : (sg1 ? d2 : d3);
                float v = (t1 + u) + w;
                v += dppf<0x124>(v);
                v += dppf<0x128>(v);
                v  = swap16_sum(v);
                v  = swap32_sum(v);
                pq[q] = v;
            }

            // ---- quantum layer (round-2 bitwise groupings) ---------------
            const float A0 = __cosf(pq[0] + pcur.x);
            const float A1 = __cosf(pq[1] + pcur.y);
            const float A2 = __cosf(pq[2] + pcur.z);
            const float A3 = __cosf(pq[3] + pcur.w);

            const float s01 = A0 * A1;
            const float s23 = A2 * A3;
            const float ezv[4] = {
                (0.99f * A1)  * s23,
                (0.99f * s01) * 1.0f,
                (0.99f * A2)  * s01,
                (0.99f * s23) * s01
            };

            float act[4];
            #pragma unroll
            for (int q = 0; q < 4; ++q) {
                const float z   = ezv[q];
                const float arg = isT ? 2.0f * fabsf(z) : -z;
                const float E   = __expf(arg);
                const float dd  = nm / (E + 1.0f);
                act[q] = isT ? copysignf(1.0f - dd, z) : dd;
            }

            // ---- canonical acts from lanes 0..3 (SGPR broadcast) ---------
            const float4 AR0 = make_float4(rdlanef(act[0],0), rdlanef(act[1],0), rdlanef(act[2],0), rdlanef(act[3],0));
            const float4 AR1 = make_float4(rdlanef(act[0],1), rdlanef(act[1],1), rdlanef(act[2],1), rdlanef(act[3],1));
            const float4 AR2 = make_float4(rdlanef(act[0],2), rdlanef(act[1],2), rdlanef(act[2],2), rdlanef(act[3],2));
            const float4 AR3 = make_float4(rdlanef(act[0],3), rdlanef(act[1],3), rdlanef(act[2],3), rdlanef(act[3],3));

            // ---- phase 2: gate matvec + cell update ----------------------
            float hxa[4];
            #pragma unroll
            for (int m = 0; m < 4; ++m) {
                const float fv = bmv[0][m] + dot4(wm[0][m], AR0);
                const float iv = bmv[1][m] + dot4(wm[1][m], AR1);
                const float gv = bmv[2][m] + dot4(wm[2][m], AR2);
                const float ov = bmv[3][m] + dot4(wm[3][m], AR3);
                cxa[k][m] = fmaf(fv, cxa[k][m], iv * gv);
                hxa[m] = ov * tanh_(cxa[k][m]);
            }
            hxv[k] = make_float4(hxa[0], hxa[1], hxa[2], hxa[3]);

            *(float4*)outp[k] = hxv[k];
            outp[k] += (size_t)BATCH * HID;
        }
    }

    #pragma unroll
    for (int k = 0; k < NB; ++k) {
        *(float4*)(out_hx + (size_t)(b0 + k) * HID + 4*l) = hxv[k];
        *(float4*)(out_cx + (size_t)(b0 + k) * HID + 4*l) =
            make_float4(cxa[k][0], cxa[k][1], cxa[k][2], cxa[k][3]);
    }
}

extern "C" void kernel_launch(void* const* d_in, const int* in_sizes, int n_in,
                              void* d_out, int out_size, void* d_ws, size_t ws_size,
                              hipStream_t stream) {
    const float* x     = (const float*)d_in[0];
    const float* w_lin = (const float*)d_in[1];
    const float* b_lin = (const float*)d_in[2];
    const float* w_map = (const float*)d_in[3];
    const float* b_map = (const float*)d_in[4];
    const float* theta = (const float*)d_in[5];
    float* out = (float*)d_out;

    const size_t pre_bytes = (size_t)SEQ * BATCH * 16 * sizeof(float);
    float* pre;
    int pstride;
    if (ws_size >= pre_bytes) {
        pre = (float*)d_ws;
        pstride = 16;
    } else {
        pre = out;                        // row s overwritten only at end of step s;
        pstride = HID;                    // reads run 2 steps ahead of the overwrite
    }

    pre_gemm<<<dim3(SEQ * 16), dim3(256), 0, stream>>>(x, w_lin, b_lin, theta, pre, pstride);
    qlstm_rec<<<dim3(BATCH / NB), dim3(64), 0, stream>>>(w_lin, w_map, b_map, pre, pstride, out);
}

// Round 7
// 484.646 us; speedup vs baseline: 3.4104x; 3.4104x over previous
//
#include <hip/hip_runtime.h>

#define SEQ   512
#define BATCH 256
#define DIN   128
#define HID   256

__device__ __forceinline__ float dot4(float4 a, float4 b) {
    return fmaf(a.x, b.x, fmaf(a.y, b.y, fmaf(a.z, b.z, a.w * b.w)));
}
__device__ __forceinline__ float tanh_(float x) {      // round-2 bitwise
    float ax = fabsf(x);
    float e  = __expf(2.0f * ax);
    float r  = 1.0f - 2.0f / (e + 1.0f);
    return copysignf(r, x);
}
template <int CTRL>
__device__ __forceinline__ float dppf(float v) {
    return __int_as_float(__builtin_amdgcn_mov_dpp(__float_as_int(v), CTRL, 0xF, 0xF, false));
}
template <int CTRL>
__device__ __forceinline__ float4 dpp4(float4 v) {
    return make_float4(dppf<CTRL>(v.x), dppf<CTRL>(v.y), dppf<CTRL>(v.z), dppf<CTRL>(v.w));
}
__device__ __forceinline__ float swap16_sum(float v) {
    float a = v, b;
    asm("v_mov_b32 %1, %0\n\tv_permlane16_swap_b32 %0, %1" : "+v"(a), "=&v"(b));
    return a + b;
}
__device__ __forceinline__ float swap32_sum(float v) {
    float a = v, b;
    asm("v_mov_b32 %1, %0\n\tv_permlane32_swap_b32 %0, %1" : "+v"(a), "=&v"(b));
    return a + b;
}
__device__ __forceinline__ float rdlanef(float v, int lane) {
    return __int_as_float(__builtin_amdgcn_readlane(__float_as_int(v), lane));
}
// Pin a value in VGPRs: opaque def the compiler can't rematerialize/reload.
__device__ __forceinline__ void pin4(float4& v) {
    asm volatile("" : "+v"(v.x), "+v"(v.y), "+v"(v.z), "+v"(v.w));
}
__device__ __forceinline__ void pin1(float& v) {
    asm volatile("" : "+v"(v));
}

// ---------------------------------------------------------------------------
// Kernel 1: pre[s,b,p] = b_lin[p] + theta[p] + sum_d w_lin[p,d] * x[s,b,d]
// (bitwise-identical to round 2)
// ---------------------------------------------------------------------------
__global__ __launch_bounds__(256, 4) void pre_gemm(
    const float* __restrict__ x,      // (S,B,D)
    const float* __restrict__ w_lin,  // (16,384) x-part = [0:128)
    const float* __restrict__ b_lin,  // (16,)
    const float* __restrict__ theta,  // (16,)
    float* pre, int pstride)
{
    __shared__ float wlds[16 * 132];
    const int t = threadIdx.x;
    for (int i = t; i < 16 * 128; i += 256) {
        int pp = i >> 7, dd = i & 127;
        wlds[pp * 132 + dd] = w_lin[pp * 384 + dd];
    }
    __syncthreads();
    const int s = blockIdx.x >> 4;
    const int b = ((blockIdx.x & 15) << 4) + (t >> 4);
    const int p = t & 15;
    const float* xr = x + ((size_t)s * BATCH + b) * DIN;
    const float* wr = &wlds[p * 132];
    float acc = b_lin[p] + theta[p];
    #pragma unroll 8
    for (int d = 0; d < 32; ++d)
        acc += dot4(*(const float4*)(xr + d * 4), *(const float4*)(wr + d * 4));
    pre[((size_t)s * BATCH + b) * pstride + p] = acc;
}

// ---------------------------------------------------------------------------
// Kernel 2: recurrence — ONE WAVE per batch element, no LDS, no barriers.
// Bitwise round-2 numerics (proven). Round-7 fix: all 144 weight floats are
// PINNED in VGPRs (asm keep-alive + waves_per_eu(1) for the 512-reg budget),
// so the serial step chain has no per-step weight reloads from memory.
// ---------------------------------------------------------------------------
__global__ __launch_bounds__(64, 1)
__attribute__((amdgpu_waves_per_eu(1, 1)))
void qlstm_rec(
    const float* __restrict__ w_lin,  // (16, 384), hx part = [128:384)
    const float* __restrict__ w_map,  // (4, 256, 4)
    const float* __restrict__ b_map,  // (4, 256)
    const float* pre, int pstride,    // may alias out (no restrict!)
    float* out)
{
    const int b = blockIdx.x;
    const int l = threadIdx.x;        // 0..63
    const int a = l & 3;              // owned gate
    const int Q = l >> 2;             // quad; partial covers hx[16Q..16Q+15]
    const bool sg1 = (Q >> 1) & 1;
    const bool sg2 = (Q >> 2) & 1;
    const bool isT = (a == 2);

    // phase-1 weights: wh4[q][c] = Wh[p=4a+q][h = 16Q+4c .. +3]
    float4 wh4[4][4];
    #pragma unroll
    for (int q = 0; q < 4; ++q)
        #pragma unroll
        for (int c = 0; c < 4; ++c) {
            wh4[q][c] = *(const float4*)(w_lin + (4*a + q) * 384 + 128 + 16*Q + 4*c);
            pin4(wh4[q][c]);
        }

    // phase-2 weights/biases for own 4 h values (h = 4l+m)
    float4 wm[4][4];
    float  bmv[4][4];
    #pragma unroll
    for (int g2 = 0; g2 < 4; ++g2) {
        #pragma unroll
        for (int m = 0; m < 4; ++m) {
            wm[g2][m] = *(const float4*)(w_map + ((size_t)(g2 * 256 + 4*l + m)) * 4);
            pin4(wm[g2][m]);
        }
        float4 bq = *(const float4*)(b_map + g2 * 256 + 4*l);
        bmv[g2][0] = bq.x; bmv[g2][1] = bq.y; bmv[g2][2] = bq.z; bmv[g2][3] = bq.w;
        pin1(bmv[g2][0]); pin1(bmv[g2][1]); pin1(bmv[g2][2]); pin1(bmv[g2][3]);
    }

    const float nm = isT ? 2.0f : 1.0f;

    const float* pb = pre + (size_t)b * pstride + 4*a;
    const size_t sstride = (size_t)BATCH * pstride;
    float4 px0 = *(const float4*)(pb);
    float4 px1 = *(const float4*)(pb + sstride);

    float4 hxv = make_float4(0.f, 0.f, 0.f, 0.f);
    float  cxa[4] = {0.f, 0.f, 0.f, 0.f};

    float* outp   = out + (size_t)b * HID + 4*l;
    float* out_hx = out + (size_t)SEQ * BATCH * HID;
    float* out_cx = out_hx + BATCH * HID;

    for (int s = 0; s < SEQ; ++s) {
        const float4 pcur = px0;
        px0 = px1;
        const int s2 = (s + 2 < SEQ) ? (s + 2) : (SEQ - 1);
        px1 = *(const float4*)(pb + (size_t)s2 * sstride);

        // ---- phase 1: quad-allgather hx -----------------------------------
        const float4 h0 = dpp4<0x00>(hxv);
        const float4 h1 = dpp4<0x55>(hxv);
        const float4 h2 = dpp4<0xAA>(hxv);
        const float4 h3 = dpp4<0xFF>(hxv);

        // sig-permuted partial order + ror4/ror8/swap16/swap32 tree
        float pq[4];
        #pragma unroll
        for (int q = 0; q < 4; ++q) {
            const float d0 = dot4(wh4[q][0], h0);
            const float d1 = dot4(wh4[q][1], h1);
            const float d2 = dot4(wh4[q][2], h2);
            const float d3 = dot4(wh4[q][3], h3);
            const float A01 = d0 + d1;
            const float A23 = d2 + d3;
            const float t1 = sg2 ? A23 : A01;
            const float u  = sg2 ? (sg1 ? d1 : d0) : (sg1 ? d3 : d2);
            const float w  = sg2 ? (sg1 ? d0 : d1) : (sg1 ? d2 : d3);
            float v = (t1 + u) + w;
            v += dppf<0x124>(v);
            v += dppf<0x128>(v);
            v  = swap16_sum(v);
            v  = swap32_sum(v);
            pq[q] = v;
        }

        // ---- quantum layer (round-2 bitwise groupings) --------------------
        const float A0 = __cosf(pq[0] + pcur.x);
        const float A1 = __cosf(pq[1] + pcur.y);
        const float A2 = __cosf(pq[2] + pcur.z);
        const float A3 = __cosf(pq[3] + pcur.w);

        const float s01 = A0 * A1;
        const float s23 = A2 * A3;
        const float ezv[4] = {
            (0.99f * A1)  * s23,
            (0.99f * s01) * 1.0f,
            (0.99f * A2)  * s01,
            (0.99f * s23) * s01
        };

        float act[4];
        #pragma unroll
        for (int q = 0; q < 4; ++q) {
            const float z   = ezv[q];
            const float arg = isT ? 2.0f * fabsf(z) : -z;
            const float E   = __expf(arg);
            const float dd  = nm / (E + 1.0f);
            act[q] = isT ? copysignf(1.0f - dd, z) : dd;
        }

        // ---- canonical acts from lanes 0..3 (SGPR broadcast) --------------
        const float4 AR0 = make_float4(rdlanef(act[0],0), rdlanef(act[1],0), rdlanef(act[2],0), rdlanef(act[3],0));
        const float4 AR1 = make_float4(rdlanef(act[0],1), rdlanef(act[1],1), rdlanef(act[2],1), rdlanef(act[3],1));
        const float4 AR2 = make_float4(rdlanef(act[0],2), rdlanef(act[1],2), rdlanef(act[2],2), rdlanef(act[3],2));
        const float4 AR3 = make_float4(rdlanef(act[0],3), rdlanef(act[1],3), rdlanef(act[2],3), rdlanef(act[3],3));

        // ---- phase 2: gate matvec + cell update ---------------------------
        float hxa[4];
        #pragma unroll
        for (int m = 0; m < 4; ++m) {
            const float fv = bmv[0][m] + dot4(wm[0][m], AR0);
            const float iv = bmv[1][m] + dot4(wm[1][m], AR1);
            const float gv = bmv[2][m] + dot4(wm[2][m], AR2);
            const float ov = bmv[3][m] + dot4(wm[3][m], AR3);
            cxa[m] = fmaf(fv, cxa[m], iv * gv);
            hxa[m] = ov * tanh_(cxa[m]);
        }
        hxv = make_float4(hxa[0], hxa[1], hxa[2], hxa[3]);

        *(float4*)outp = hxv;
        outp += (size_t)BATCH * HID;
    }

    *(float4*)(out_hx + (size_t)b * HID + 4*l) = hxv;
    *(float4*)(out_cx + (size_t)b * HID + 4*l) = make_float4(cxa[0], cxa[1], cxa[2], cxa[3]);
}

extern "C" void kernel_launch(void* const* d_in, const int* in_sizes, int n_in,
                              void* d_out, int out_size, void* d_ws, size_t ws_size,
                              hipStream_t stream) {
    const float* x     = (const float*)d_in[0];
    const float* w_lin = (const float*)d_in[1];
    const float* b_lin = (const float*)d_in[2];
    const float* w_map = (const float*)d_in[3];
    const float* b_map = (const float*)d_in[4];
    const float* theta = (const float*)d_in[5];
    float* out = (float*)d_out;

    const size_t pre_bytes = (size_t)SEQ * BATCH * 16 * sizeof(float);
    float* pre;
    int pstride;
    if (ws_size >= pre_bytes) {
        pre = (float*)d_ws;
        pstride = 16;
    } else {
        pre = out;                        // row s overwritten only at end of step s;
        pstride = HID;                    // reads run 2 steps ahead of the overwrite
    }

    pre_gemm<<<dim3(SEQ * 16), dim3(256), 0, stream>>>(x, w_lin, b_lin, theta, pre, pstride);
    qlstm_rec<<<dim3(BATCH), dim3(64), 0, stream>>>(w_lin, w_map, b_map, pre, pstride, out);
}

// Round 9
// 425.291 us; speedup vs baseline: 3.8864x; 1.1396x over previous
//
#include <hip/hip_runtime.h>

#define SEQ   512
#define BATCH 256
#define DIN   128
#define HID   256
#define NOISE 0.99f

__device__ __forceinline__ float dot4(float4 a, float4 b) {
    return fmaf(a.x, b.x, fmaf(a.y, b.y, fmaf(a.z, b.z, a.w * b.w)));
}
__device__ __forceinline__ float sigmoid_(float x) {
    return 1.0f / (1.0f + __expf(-x));
}
__device__ __forceinline__ float tanh_(float x) {
    float ax = fabsf(x);
    float e  = __expf(2.0f * ax);
    float r  = 1.0f - 2.0f / (e + 1.0f);
    return copysignf(r, x);
}
template <int CTRL>
__device__ __forceinline__ float dppf(float v) {
    return __int_as_float(__builtin_amdgcn_mov_dpp(__float_as_int(v), CTRL, 0xF, 0xF, false));
}
__device__ __forceinline__ float swap16_sum(float v) {
    float a = v, b;
    asm("v_mov_b32 %1, %0\n\tv_permlane16_swap_b32 %0, %1" : "+v"(a), "=&v"(b));
    return a + b;
}
__device__ __forceinline__ float swap32_sum(float v) {
    float a = v, b;
    asm("v_mov_b32 %1, %0\n\tv_permlane32_swap_b32 %0, %1" : "+v"(a), "=&v"(b));
    return a + b;
}
__device__ __forceinline__ float rdlanef(float v, int lane) {
    return __int_as_float(__builtin_amdgcn_readlane(__float_as_int(v), lane));
}

// ---------------------------------------------------------------------------
// Kernel 1: pre[s,b,p] = b_lin[p] + theta[p] + sum_d w_lin[p,d] * x[s,b,d]
// (unchanged, validated rounds 2..7)
// ---------------------------------------------------------------------------
__global__ __launch_bounds__(256, 4) void pre_gemm(
    const float* __restrict__ x,      // (S,B,D)
    const float* __restrict__ w_lin,  // (16,384) x-part = [0:128)
    const float* __restrict__ b_lin,  // (16,)
    const float* __restrict__ theta,  // (16,)
    float* pre, int pstride)
{
    __shared__ float wlds[16 * 132];
    const int t = threadIdx.x;
    for (int i = t; i < 16 * 128; i += 256) {
        int pp = i >> 7, dd = i & 127;
        wlds[pp * 132 + dd] = w_lin[pp * 384 + dd];
    }
    __syncthreads();
    const int s = blockIdx.x >> 4;
    const int b = ((blockIdx.x & 15) << 4) + (t >> 4);
    const int p = t & 15;
    const float* xr = x + ((size_t)s * BATCH + b) * DIN;
    const float* wr = &wlds[p * 132];
    float acc = b_lin[p] + theta[p];
    #pragma unroll 8
    for (int d = 0; d < 32; ++d)
        acc += dot4(*(const float4*)(xr + d * 4), *(const float4*)(wr + d * 4));
    pre[((size_t)s * BATCH + b) * pstride + p] = acc;
}

// ---------------------------------------------------------------------------
// Kernel 2: persistent recurrence. ROUND-2 arithmetic, restructured to ONE
// barrier per step:
//  - every wave redundantly computes ALL FOUR gates' phase 1 with the exact
//    round-2 per-gate instruction sequence (same weights, same LDS reads,
//    same DPP tree) -> acts at lanes 0..3 are bitwise round-2 values
//  - acts gathered IN-WAVE via v_readlane from lanes 0..3 (no acts LDS, no B1)
//  - hx exchanged through double-buffered LDS with a single barrier per step
// ---------------------------------------------------------------------------
__global__ __launch_bounds__(256, 1) void qlstm_rec(
    const float* __restrict__ w_lin,  // (16, 384), hx part = [128:384)
    const float* __restrict__ w_map,  // (4, 256, 4)
    const float* __restrict__ b_map,  // (4, 256)
    const float* pre, int pstride,    // may alias out (no restrict!)
    float* out)
{
    const int b = blockIdx.x;
    const int t = threadIdx.x;
    const int l = t & 63;
    const int q = l & 3;             // qubit (quad lane)
    const int j = l >> 2;            // 16 reduction slots of 16 h each
    const int sig = (j >> 1) & 3;    // bank-conflict swizzle (round 2)

    __shared__ __align__(16) float hx_lds[2][HID];

    // phase-1 weights for ALL four gates: wh[g][k] = Wh[p=4g+q][16j + (k^sig)*4 ..]
    float4 wh[4][4];
    #pragma unroll
    for (int gg = 0; gg < 4; ++gg)
        #pragma unroll
        for (int k = 0; k < 4; ++k)
            wh[gg][k] = *(const float4*)(w_lin + ((gg << 2) | q) * 384 + 128 + j * 16 + ((k ^ sig) << 2));

    // phase-2 weights: thread t owns h = t (round 2 verbatim)
    const float4 wm0 = ((const float4*)w_map)[0 * 256 + t];
    const float4 wm1 = ((const float4*)w_map)[1 * 256 + t];
    const float4 wm2 = ((const float4*)w_map)[2 * 256 + t];
    const float4 wm3 = ((const float4*)w_map)[3 * 256 + t];
    const float bm0 = b_map[t];
    const float bm1 = b_map[256 + t];
    const float bm2 = b_map[512 + t];
    const float bm3 = b_map[768 + t];

    // swizzled hx read offsets (round 2)
    const int o0 = j * 16 + ((0 ^ sig) << 2);
    const int o1 = j * 16 + ((1 ^ sig) << 2);
    const int o2 = j * 16 + ((2 ^ sig) << 2);
    const int o3 = j * 16 + ((3 ^ sig) << 2);

    // pre prefetch, 2 steps ahead, for all four gates' p = 4g+q
    const size_t sstride = (size_t)BATCH * pstride;
    const float* pb[4];
    float px0[4], px1[4];
    #pragma unroll
    for (int gg = 0; gg < 4; ++gg) {
        pb[gg]  = pre + (size_t)b * pstride + ((gg << 2) | q);
        px0[gg] = pb[gg][0];
        px1[gg] = pb[gg][sstride];
    }

    hx_lds[0][t] = 0.0f;
    float hx = 0.0f, cx = 0.0f;
    float* out_seq = out;
    float* out_hx  = out + (size_t)SEQ * BATCH * HID;
    float* out_cx  = out_hx + BATCH * HID;
    __syncthreads();

    for (int s = 0; s < SEQ; ++s) {
        const int s2 = (s + 2 < SEQ) ? s + 2 : SEQ - 1;

        // ---- phase 1 for all four gates (round-2 bitwise per gate) --------
        const float* hb = hx_lds[s & 1];
        const float4 ha0 = *(const float4*)(hb + o0);
        const float4 ha1 = *(const float4*)(hb + o1);
        const float4 ha2 = *(const float4*)(hb + o2);
        const float4 ha3 = *(const float4*)(hb + o3);

        float actg[4];
        #pragma unroll
        for (int gg = 0; gg < 4; ++gg) {
            float acc = dot4(wh[gg][0], ha0) + dot4(wh[gg][1], ha1)
                      + dot4(wh[gg][2], ha2) + dot4(wh[gg][3], ha3);
            acc += dppf<0x124>(acc);     // row_ror:4  (slot bit 0)
            acc += dppf<0x128>(acc);     // row_ror:8  (slot bit 1)
            acc  = swap16_sum(acc);      // slot bit 2
            acc  = swap32_sum(acc);      // slot bit 3

            const float pxu = px0[gg];
            px0[gg] = px1[gg];
            px1[gg] = pb[gg][(size_t)s2 * sstride];

            const float A  = __cosf(acc + pxu);
            const float Bv = dppf<0xB1>(A);      // C_{q^1}
            const float Cv = dppf<0x4E>(A);      // C_{q^2}
            const float Dv = dppf<0x4E>(Bv);     // C_{q^3}

            const float t1 = Cv * Dv;
            const float u  = (q & 1) ? (A * Bv) : ((q == 2) ? A : Bv);
            const float v  = (q == 1) ? 1.0f : t1;
            const float ez = NOISE * u * v;
            actg[gg] = (gg == 2) ? tanh_(ez) : sigmoid_(ez);
        }

        // ---- in-wave act gather from canonical lanes 0..3 (== round 2's
        //      j==0 acts_lds values, bitwise) ------------------------------
        float ar[4][4];
        #pragma unroll
        for (int gg = 0; gg < 4; ++gg)
            #pragma unroll
            for (int qq = 0; qq < 4; ++qq)
                ar[gg][qq] = rdlanef(actg[gg], qq);

        // ---- phase 2: gate matvec + cell update (round-2 fmaf chains) -----
        const float fv = bm0 + fmaf(wm0.x, ar[0][0], fmaf(wm0.y, ar[0][1], fmaf(wm0.z, ar[0][2], wm0.w * ar[0][3])));
        const float iv = bm1 + fmaf(wm1.x, ar[1][0], fmaf(wm1.y, ar[1][1], fmaf(wm1.z, ar[1][2], wm1.w * ar[1][3])));
        const float gv = bm2 + fmaf(wm2.x, ar[2][0], fmaf(wm2.y, ar[2][1], fmaf(wm2.z, ar[2][2], wm2.w * ar[2][3])));
        const float ov = bm3 + fmaf(wm3.x, ar[3][0], fmaf(wm3.y, ar[3][1], fmaf(wm3.z, ar[3][2], wm3.w * ar[3][3])));

        cx = fmaf(fv, cx, iv * gv);
        hx = ov * tanh_(cx);

        hx_lds[(s + 1) & 1][t] = hx;     // other buffer: no race with reads
        out_seq[((size_t)s * BATCH + b) * HID + t] = hx;
        __syncthreads();                 // single barrier per step
    }

    out_hx[(size_t)b * HID + t] = hx;
    out_cx[(size_t)b * HID + t] = cx;
}

extern "C" void kernel_launch(void* const* d_in, const int* in_sizes, int n_in,
                              void* d_out, int out_size, void* d_ws, size_t ws_size,
                              hipStream_t stream) {
    const float* x     = (const float*)d_in[0];
    const float* w_lin = (const float*)d_in[1];
    const float* b_lin = (const float*)d_in[2];
    const float* w_map = (const float*)d_in[3];
    const float* b_map = (const float*)d_in[4];
    const float* theta = (const float*)d_in[5];
    float* out = (float*)d_out;

    const size_t pre_bytes = (size_t)SEQ * BATCH * 16 * sizeof(float);
    float* pre;
    int pstride;
    if (ws_size >= pre_bytes) {          // scratch big enough: clean path
        pre = (float*)d_ws;
        pstride = 16;
    } else {                              // stash pre in the not-yet-written out rows
        pre = out;                        // row s overwritten only at end of step s;
        pstride = HID;                    // reads run 2 steps ahead of the overwrite
    }

    pre_gemm<<<dim3(SEQ * 16), dim3(256), 0, stream>>>(x, w_lin, b_lin, theta, pre, pstride);
    qlstm_rec<<<dim3(BATCH), dim3(256), 0, stream>>>(w_lin, w_map, b_map, pre, pstride, out);
}

// Round 10
// 285.375 us; speedup vs baseline: 5.7918x; 1.4903x over previous
//
#include <hip/hip_runtime.h>

#define SEQ   512
#define BATCH 256
#define DIN   128
#define HID   256
#define NOISE 0.99f

__device__ __forceinline__ float dot4(float4 a, float4 b) {
    return fmaf(a.x, b.x, fmaf(a.y, b.y, fmaf(a.z, b.z, a.w * b.w)));
}
__device__ __forceinline__ float sigmoid_(float x) {
    return 1.0f / (1.0f + __expf(-x));
}
__device__ __forceinline__ float tanh_(float x) {
    float ax = fabsf(x);
    float e  = __expf(2.0f * ax);
    float r  = 1.0f - 2.0f / (e + 1.0f);
    return copysignf(r, x);
}

// DPP move: quad_perm / row_ror within 16-lane rows (VALU pipe)
template <int CTRL>
__device__ __forceinline__ float dppmov(float v) {
    return __int_as_float(__builtin_amdgcn_mov_dpp(__float_as_int(v), CTRL, 0xF, 0xF, false));
}
// xor-16 / xor-32 butterfly sums via permlane swaps (VALU) — round-2 proven
__device__ __forceinline__ float swap16_sum(float v) {
    float a = v, b;
    asm("v_mov_b32 %1, %0\n\tv_permlane16_swap_b32 %0, %1" : "+v"(a), "=&v"(b));
    return a + b;
}
__device__ __forceinline__ float swap32_sum(float v) {
    float a = v, b;
    asm("v_mov_b32 %1, %0\n\tv_permlane32_swap_b32 %0, %1" : "+v"(a), "=&v"(b));
    return a + b;
}

// LDS-only barrier: waits lgkmcnt(0) for LDS visibility, does NOT drain vmcnt.
// __syncthreads() would emit s_waitcnt vmcnt(0) lgkmcnt(0) and put the per-step
// global store + prefetch-load latency on the serial chain (round-10 theory).
__device__ __forceinline__ void barrier_lds() {
    asm volatile("s_waitcnt lgkmcnt(0)\n\ts_barrier" ::: "memory");
}

// ---------------------------------------------------------------------------
// Kernel 1: pre[s,b,p] = b_lin[p] + theta[p] + sum_d w_lin[p,d] * x[s,b,d]
// (unchanged, validated rounds 2..9)
// ---------------------------------------------------------------------------
__global__ __launch_bounds__(256, 4) void pre_gemm(
    const float* __restrict__ x,      // (S,B,D)
    const float* __restrict__ w_lin,  // (16,384) x-part = [0:128)
    const float* __restrict__ b_lin,  // (16,)
    const float* __restrict__ theta,  // (16,)
    float* pre, int pstride)
{
    __shared__ float wlds[16 * 132];
    const int t = threadIdx.x;
    for (int i = t; i < 16 * 128; i += 256) {
        int pp = i >> 7, dd = i & 127;
        wlds[pp * 132 + dd] = w_lin[pp * 384 + dd];
    }
    __syncthreads();
    const int s = blockIdx.x >> 4;
    const int b = ((blockIdx.x & 15) << 4) + (t >> 4);
    const int p = t & 15;
    const float* xr = x + ((size_t)s * BATCH + b) * DIN;
    const float* wr = &wlds[p * 132];
    float acc = b_lin[p] + theta[p];
    #pragma unroll 8
    for (int d = 0; d < 32; ++d)
        acc += dot4(*(const float4*)(xr + d * 4), *(const float4*)(wr + d * 4));
    pre[((size_t)s * BATCH + b) * pstride + p] = acc;
}

// ---------------------------------------------------------------------------
// Kernel 2: persistent recurrence — ROUND-2 KERNEL VERBATIM (bitwise-passing
// arithmetic, 4 waves, all-VALU comms) with exactly one change: both
// __syncthreads() replaced by barrier_lds() so the per-step global store and
// pre-prefetch load stay in flight across the barriers.
// ---------------------------------------------------------------------------
__global__ __launch_bounds__(256, 1) void qlstm_rec(
    const float* __restrict__ w_lin,  // (16, 384), hx part = [128:384)
    const float* __restrict__ w_map,  // (4, 256, 4)
    const float* __restrict__ b_map,  // (4, 256)
    const float* pre, int pstride,    // may alias out (no restrict!)
    float* out)
{
    const int b = blockIdx.x;
    const int t = threadIdx.x;
    const int l = t & 63;
    const int g = t >> 6;        // wave index == gate
    const int q = l & 3;
    const int j = l >> 2;        // 0..15
    const int p = (g << 2) | q;

    __shared__ __align__(16) float hx_lds[HID];
    __shared__ __align__(16) float acts_lds[16];

    // hx-part weights; LDS-read slot k returns hx slot (k ^ sig), so load the
    // matching weight slot into register k (swizzle folded into init).
    const int sig = (j >> 1) & 3;
    const float* wp = w_lin + p * 384 + 128 + j * 16;
    const float4 wh0 = *(const float4*)(wp + ((0 ^ sig) << 2));
    const float4 wh1 = *(const float4*)(wp + ((1 ^ sig) << 2));
    const float4 wh2 = *(const float4*)(wp + ((2 ^ sig) << 2));
    const float4 wh3 = *(const float4*)(wp + ((3 ^ sig) << 2));

    // phase-2 weights: thread t owns h = t
    const float4 wm0 = ((const float4*)w_map)[0 * 256 + t];
    const float4 wm1 = ((const float4*)w_map)[1 * 256 + t];
    const float4 wm2 = ((const float4*)w_map)[2 * 256 + t];
    const float4 wm3 = ((const float4*)w_map)[3 * 256 + t];
    const float bm0 = b_map[t];
    const float bm1 = b_map[256 + t];
    const float bm2 = b_map[512 + t];
    const float bm3 = b_map[768 + t];

    // bank-conflict-free hx read addresses (XOR swizzle on the read side)
    const float* hr = &hx_lds[j * 16];
    const float* hr0 = hr + ((0 ^ sig) << 2);
    const float* hr1 = hr + ((1 ^ sig) << 2);
    const float* hr2 = hr + ((2 ^ sig) << 2);
    const float* hr3 = hr + ((3 ^ sig) << 2);

    // pre prefetch: 2 steps ahead (safe vs. the out-row overwrite when aliased)
    const float*  pb      = pre + (size_t)b * pstride + p;
    const size_t  sstride = (size_t)BATCH * pstride;
    float px0 = pb[0];
    float px1 = pb[sstride];

    hx_lds[t] = 0.0f;
    float hx = 0.0f, cx = 0.0f;
    float* out_seq = out;
    float* out_hx  = out + (size_t)SEQ * BATCH * HID;
    float* out_cx  = out_hx + BATCH * HID;
    barrier_lds();

    for (int s = 0; s < SEQ; ++s) {
        const float pxu = px0;
        px0 = px1;
        const int s2 = (s + 2 < SEQ) ? s + 2 : SEQ - 1;
        px1 = pb[(size_t)s2 * sstride];

        // ---- phase 1: hx matvec + reduce (VALU comms) + quantum + act ------
        const float4 ha0 = *(const float4*)hr0;
        const float4 ha1 = *(const float4*)hr1;
        const float4 ha2 = *(const float4*)hr2;
        const float4 ha3 = *(const float4*)hr3;
        float acc = dot4(wh0, ha0) + dot4(wh1, ha1)
                  + dot4(wh2, ha2) + dot4(wh3, ha3);
        acc += dppmov<0x124>(acc);   // += lane+4  (row_ror:4)
        acc += dppmov<0x128>(acc);   // += lane+8  (row_ror:8)
        acc  = swap16_sum(acc);      // += lane^16
        acc  = swap32_sum(acc);      // += lane^32

        const float A  = __cosf(acc + pxu);      // pre includes b_lin + theta
        const float Bv = dppmov<0xB1>(A);        // quad_perm xor1 -> C_{q^1}
        const float Cv = dppmov<0x4E>(A);        // quad_perm xor2 -> C_{q^2}
        const float Dv = dppmov<0x4E>(Bv);       //                -> C_{q^3}

        const float t1 = Cv * Dv;
        const float u  = (q & 1) ? (A * Bv) : ((q == 2) ? A : Bv);
        const float v  = (q == 1) ? 1.0f : t1;
        const float ez = NOISE * u * v;
        const float act = (g == 2) ? tanh_(ez) : sigmoid_(ez);
        if (l < 4) acts_lds[(g << 2) | l] = act;
        barrier_lds();                            // B1: acts visible (LDS only)

        // ---- phase 2: gate matvec + cell update ---------------------------
        const float4 a0 = *(const float4*)&acts_lds[0];
        const float4 a1 = *(const float4*)&acts_lds[4];
        const float4 a2 = *(const float4*)&acts_lds[8];
        const float4 a3 = *(const float4*)&acts_lds[12];

        const float fv = bm0 + dot4(wm0, a0);
        const float iv = bm1 + dot4(wm1, a1);
        const float gv = bm2 + dot4(wm2, a2);
        const float ov = bm3 + dot4(wm3, a3);

        cx = fmaf(fv, cx, iv * gv);
        hx = ov * tanh_(cx);

        hx_lds[t] = hx;
        out_seq[((size_t)s * BATCH + b) * HID + t] = hx;
        barrier_lds();                            // B2: hx visible (LDS only)
    }

    out_hx[(size_t)b * HID + t] = hx;
    out_cx[(size_t)b * HID + t] = cx;
}

extern "C" void kernel_launch(void* const* d_in, const int* in_sizes, int n_in,
                              void* d_out, int out_size, void* d_ws, size_t ws_size,
                              hipStream_t stream) {
    const float* x     = (const float*)d_in[0];
    const float* w_lin = (const float*)d_in[1];
    const float* b_lin = (const float*)d_in[2];
    const float* w_map = (const float*)d_in[3];
    const float* b_map = (const float*)d_in[4];
    const float* theta = (const float*)d_in[5];
    float* out = (float*)d_out;

    const size_t pre_bytes = (size_t)SEQ * BATCH * 16 * sizeof(float);
    float* pre;
    int pstride;
    if (ws_size >= pre_bytes) {          // scratch big enough: clean path
        pre = (float*)d_ws;
        pstride = 16;
    } else {                              // stash pre in the not-yet-written out rows
        pre = out;                        // row s overwritten only at end of step s;
        pstride = HID;                    // reads run 2 steps ahead of the overwrite
    }

    pre_gemm<<<dim3(SEQ * 16), dim3(256), 0, stream>>>(x, w_lin, b_lin, theta, pre, pstride);
    qlstm_rec<<<dim3(BATCH), dim3(256), 0, stream>>>(w_lin, w_map, b_map, pre, pstride, out);
}

// Round 11
// 273.943 us; speedup vs baseline: 6.0335x; 1.0417x over previous
//
#include <hip/hip_runtime.h>

#define SEQ   512
#define BATCH 256
#define DIN   128
#define HID   256
#define NOISE 0.99f

__device__ __forceinline__ float dot4(float4 a, float4 b) {
    return fmaf(a.x, b.x, fmaf(a.y, b.y, fmaf(a.z, b.z, a.w * b.w)));
}
// round-2 structure with v_rcp replacing the exact division.
// Evidence (rounds 3 vs 4): rcp-vs-div produced bit-identical output error
// under an association change; rcp's own contribution is below bf16 quantum.
__device__ __forceinline__ float sigmoid_(float x) {
    return __builtin_amdgcn_rcpf(1.0f + __expf(-x));
}
__device__ __forceinline__ float tanh_(float x) {
    float ax = fabsf(x);
    float e  = __expf(2.0f * ax);
    float t  = __builtin_amdgcn_rcpf(e + 1.0f);
    float r  = 1.0f - 2.0f * t;          // 2*t exact; one rounding, like div path
    return copysignf(r, x);
}

// DPP move: quad_perm / row_ror within 16-lane rows (VALU pipe)
template <int CTRL>
__device__ __forceinline__ float dppmov(float v) {
    return __int_as_float(__builtin_amdgcn_mov_dpp(__float_as_int(v), CTRL, 0xF, 0xF, false));
}
// xor-16 / xor-32 butterfly sums via permlane swaps (VALU) — round-2 proven
__device__ __forceinline__ float swap16_sum(float v) {
    float a = v, b;
    asm("v_mov_b32 %1, %0\n\tv_permlane16_swap_b32 %0, %1" : "+v"(a), "=&v"(b));
    return a + b;
}
__device__ __forceinline__ float swap32_sum(float v) {
    float a = v, b;
    asm("v_mov_b32 %1, %0\n\tv_permlane32_swap_b32 %0, %1" : "+v"(a), "=&v"(b));
    return a + b;
}

// LDS-only barrier: waits lgkmcnt(0) for LDS visibility, does NOT drain vmcnt
// (keeps the per-step global store + pre-prefetch load in flight — round 10,
// measured −25 cy/step).
__device__ __forceinline__ void barrier_lds() {
    asm volatile("s_waitcnt lgkmcnt(0)\n\ts_barrier" ::: "memory");
}

// ---------------------------------------------------------------------------
// Kernel 1: pre[s,b,p] = b_lin[p] + theta[p] + sum_d w_lin[p,d] * x[s,b,d]
// (unchanged, validated rounds 2..10)
// ---------------------------------------------------------------------------
__global__ __launch_bounds__(256, 4) void pre_gemm(
    const float* __restrict__ x,      // (S,B,D)
    const float* __restrict__ w_lin,  // (16,384) x-part = [0:128)
    const float* __restrict__ b_lin,  // (16,)
    const float* __restrict__ theta,  // (16,)
    float* pre, int pstride)
{
    __shared__ float wlds[16 * 132];
    const int t = threadIdx.x;
    for (int i = t; i < 16 * 128; i += 256) {
        int pp = i >> 7, dd = i & 127;
        wlds[pp * 132 + dd] = w_lin[pp * 384 + dd];
    }
    __syncthreads();
    const int s = blockIdx.x >> 4;
    const int b = ((blockIdx.x & 15) << 4) + (t >> 4);
    const int p = t & 15;
    const float* xr = x + ((size_t)s * BATCH + b) * DIN;
    const float* wr = &wlds[p * 132];
    float acc = b_lin[p] + theta[p];
    #pragma unroll 8
    for (int d = 0; d < 32; ++d)
        acc += dot4(*(const float4*)(xr + d * 4), *(const float4*)(wr + d * 4));
    pre[((size_t)s * BATCH + b) * pstride + p] = acc;
}

// ---------------------------------------------------------------------------
// Kernel 2: persistent recurrence — round-10 kernel (round-2 bitwise
// arithmetic, 4 waves, all-VALU comms, LDS-only barriers) with ONE change:
// the two exact divisions (sigmoid, tanh) use v_rcp.
// ---------------------------------------------------------------------------
__global__ __launch_bounds__(256, 1) void qlstm_rec(
    const float* __restrict__ w_lin,  // (16, 384), hx part = [128:384)
    const float* __restrict__ w_map,  // (4, 256, 4)
    const float* __restrict__ b_map,  // (4, 256)
    const float* pre, int pstride,    // may alias out (no restrict!)
    float* out)
{
    const int b = blockIdx.x;
    const int t = threadIdx.x;
    const int l = t & 63;
    const int g = t >> 6;        // wave index == gate
    const int q = l & 3;
    const int j = l >> 2;        // 0..15
    const int p = (g << 2) | q;

    __shared__ __align__(16) float hx_lds[HID];
    __shared__ __align__(16) float acts_lds[16];

    // hx-part weights; LDS-read slot k returns hx slot (k ^ sig), so load the
    // matching weight slot into register k (swizzle folded into init).
    const int sig = (j >> 1) & 3;
    const float* wp = w_lin + p * 384 + 128 + j * 16;
    const float4 wh0 = *(const float4*)(wp + ((0 ^ sig) << 2));
    const float4 wh1 = *(const float4*)(wp + ((1 ^ sig) << 2));
    const float4 wh2 = *(const float4*)(wp + ((2 ^ sig) << 2));
    const float4 wh3 = *(const float4*)(wp + ((3 ^ sig) << 2));

    // phase-2 weights: thread t owns h = t
    const float4 wm0 = ((const float4*)w_map)[0 * 256 + t];
    const float4 wm1 = ((const float4*)w_map)[1 * 256 + t];
    const float4 wm2 = ((const float4*)w_map)[2 * 256 + t];
    const float4 wm3 = ((const float4*)w_map)[3 * 256 + t];
    const float bm0 = b_map[t];
    const float bm1 = b_map[256 + t];
    const float bm2 = b_map[512 + t];
    const float bm3 = b_map[768 + t];

    // bank-conflict-free hx read addresses (XOR swizzle on the read side)
    const float* hr = &hx_lds[j * 16];
    const float* hr0 = hr + ((0 ^ sig) << 2);
    const float* hr1 = hr + ((1 ^ sig) << 2);
    const float* hr2 = hr + ((2 ^ sig) << 2);
    const float* hr3 = hr + ((3 ^ sig) << 2);

    // pre prefetch: 2 steps ahead (safe vs. the out-row overwrite when aliased)
    const float*  pb      = pre + (size_t)b * pstride + p;
    const size_t  sstride = (size_t)BATCH * pstride;
    float px0 = pb[0];
    float px1 = pb[sstride];

    hx_lds[t] = 0.0f;
    float hx = 0.0f, cx = 0.0f;
    float* out_seq = out;
    float* out_hx  = out + (size_t)SEQ * BATCH * HID;
    float* out_cx  = out_hx + BATCH * HID;
    barrier_lds();

    for (int s = 0; s < SEQ; ++s) {
        const float pxu = px0;
        px0 = px1;
        const int s2 = (s + 2 < SEQ) ? s + 2 : SEQ - 1;
        px1 = pb[(size_t)s2 * sstride];

        // ---- phase 1: hx matvec + reduce (VALU comms) + quantum + act ------
        const float4 ha0 = *(const float4*)hr0;
        const float4 ha1 = *(const float4*)hr1;
        const float4 ha2 = *(const float4*)hr2;
        const float4 ha3 = *(const float4*)hr3;
        float acc = dot4(wh0, ha0) + dot4(wh1, ha1)
                  + dot4(wh2, ha2) + dot4(wh3, ha3);
        acc += dppmov<0x124>(acc);   // += lane+4  (row_ror:4)
        acc += dppmov<0x128>(acc);   // += lane+8  (row_ror:8)
        acc  = swap16_sum(acc);      // += lane^16
        acc  = swap32_sum(acc);      // += lane^32

        const float A  = __cosf(acc + pxu);      // pre includes b_lin + theta
        const float Bv = dppmov<0xB1>(A);        // quad_perm xor1 -> C_{q^1}
        const float Cv = dppmov<0x4E>(A);        // quad_perm xor2 -> C_{q^2}
        const float Dv = dppmov<0x4E>(Bv);       //                -> C_{q^3}

        const float t1 = Cv * Dv;
        const float u  = (q & 1) ? (A * Bv) : ((q == 2) ? A : Bv);
        const float v  = (q == 1) ? 1.0f : t1;
        const float ez = NOISE * u * v;
        const float act = (g == 2) ? tanh_(ez) : sigmoid_(ez);
        if (l < 4) acts_lds[(g << 2) | l] = act;
        barrier_lds();                            // B1: acts visible (LDS only)

        // ---- phase 2: gate matvec + cell update ---------------------------
        const float4 a0 = *(const float4*)&acts_lds[0];
        const float4 a1 = *(const float4*)&acts_lds[4];
        const float4 a2 = *(const float4*)&acts_lds[8];
        const float4 a3 = *(const float4*)&acts_lds[12];

        const float fv = bm0 + dot4(wm0, a0);
        const float iv = bm1 + dot4(wm1, a1);
        const float gv = bm2 + dot4(wm2, a2);
        const float ov = bm3 + dot4(wm3, a3);

        cx = fmaf(fv, cx, iv * gv);
        hx = ov * tanh_(cx);

        hx_lds[t] = hx;
        out_seq[((size_t)s * BATCH + b) * HID + t] = hx;
        barrier_lds();                            // B2: hx visible (LDS only)
    }

    out_hx[(size_t)b * HID + t] = hx;
    out_cx[(size_t)b * HID + t] = cx;
}

extern "C" void kernel_launch(void* const* d_in, const int* in_sizes, int n_in,
                              void* d_out, int out_size, void* d_ws, size_t ws_size,
                              hipStream_t stream) {
    const float* x     = (const float*)d_in[0];
    const float* w_lin = (const float*)d_in[1];
    const float* b_lin = (const float*)d_in[2];
    const float* w_map = (const float*)d_in[3];
    const float* b_map = (const float*)d_in[4];
    const float* theta = (const float*)d_in[5];
    float* out = (float*)d_out;

    const size_t pre_bytes = (size_t)SEQ * BATCH * 16 * sizeof(float);
    float* pre;
    int pstride;
    if (ws_size >= pre_bytes) {          // scratch big enough: clean path
        pre = (float*)d_ws;
        pstride = 16;
    } else {                              // stash pre in the not-yet-written out rows
        pre = out;                        // row s overwritten only at end of step s;
        pstride = HID;                    // reads run 2 steps ahead of the overwrite
    }

    pre_gemm<<<dim3(SEQ * 16), dim3(256), 0, stream>>>(x, w_lin, b_lin, theta, pre, pstride);
    qlstm_rec<<<dim3(BATCH), dim3(256), 0, stream>>>(w_lin, w_map, b_map, pre, pstride, out);
}